// Round 1
// baseline (478.362 us; speedup 1.0000x reference)
//
#include <hip/hip_runtime.h>

typedef _Float16 f16;
typedef __attribute__((ext_vector_type(8))) _Float16 f16x8;
typedef __attribute__((ext_vector_type(4))) _Float16 f16x4;
typedef __attribute__((ext_vector_type(4))) float    f32x4;

#define MFMA(a,b,c) __builtin_amdgcn_mfma_f32_16x16x32_f16(a,b,c,0,0,0)

// problem constants (fixed-shape problem)
constexpr int Bc = 2, Nc = 65536, Cc = 256, Hc = 8, Dc = 64, Sc = 64;
constexpr int CHUNK  = 256;               // tokens per block
constexpr int NCHUNK = Bc * Nc / CHUNK;   // 512
constexpr int LDA    = 72;                // padded LDS row stride (f16 elems): +8 pad -> 2-way (free) bank pattern

// ---- workspace layout (bytes) ----
// 0       : Tg    float[16*4096]  (262144)   accumulator for unnormalized slice_tokens
// 262144  : normg float[16*64]    (4096)     accumulator for slice_norm
// 266240  : WT    f16[8*128*256]  (524288)   [h][n(0..63=W_x col, 64..127=W_fx col)][k]
// 790528  : WsT   f16[64*64]      (8192)     [s][d] = W_slice[d][s]
// total 798720 bytes

__device__ __forceinline__ f32x4 splat4(float v) { f32x4 r; r.x=v; r.y=v; r.z=v; r.w=v; return r; }

__global__ void zero_ws(float* p) {
  int i = blockIdx.x * 256 + threadIdx.x;   // grid sized exactly: 66560 floats (T + norm)
  p[i] = 0.0f;
}

__global__ void prep_w(const float* __restrict__ Wx, const float* __restrict__ Wfx,
                       const float* __restrict__ Wsl, f16* __restrict__ WT,
                       f16* __restrict__ WsT) {
  int idx = blockIdx.x * 256 + threadIdx.x;
  if (idx < 256 * 512) {                   // transpose + f16-convert both weight matrices
    int k = idx >> 9, col = idx & 511;     // coalesced reads of W_x / W_fx rows
    int h = col >> 6, n = col & 63;
    WT[(h*128 + n     )*256 + k] = (f16)Wx [idx];
    WT[(h*128 + 64 + n)*256 + k] = (f16)Wfx[idx];
  } else {
    int j = idx - 256 * 512;               // [0,4096): W_slice transpose
    int s = j >> 6, d = j & 63;
    WsT[s*64 + d] = (f16)Wsl[d*64 + s];
  }
}

__global__ __launch_bounds__(256, 2)
void fused_main(const float* __restrict__ x,   const float* __restrict__ bx,
                const float* __restrict__ bfx, const float* __restrict__ bsl,
                const float* __restrict__ temp, const f16* __restrict__ WT,
                const f16* __restrict__ WsT,   float* __restrict__ Tg,
                float* __restrict__ normg) {
  __shared__ alignas(16) f16 sm_xt [64  * LDA];  // x sub-tile   [tok][k]
  __shared__ alignas(16) f16 sm_wt [128 * LDA];  // weight tile  [n][k]
  __shared__ alignas(16) f16 sm_px [64  * LDA];  // projected_x  [tok][d]  (A-layout for sp)
  __shared__ alignas(16) f16 sm_fxT[64  * LDA];  // fx^T         [d][tok]  (B-layout for T)
  __shared__ alignas(16) f16 sm_wT [64  * LDA];  // weights^T    [s][tok]  (A-layout for T)
  __shared__ alignas(16) f16 sm_ws [64  * LDA];  // W_slice^T    [s][d]    (B-layout for sp)

  const int chunk = blockIdx.x, h = blockIdx.y;
  const int tid = threadIdx.x;
  const int wv = tid >> 6, lane = tid & 63, quad = lane >> 4, ln = lane & 15;
  const long tokBase = (long)chunk * CHUNK;      // flat (b,n) token index
  const int b  = (int)(tokBase >> 16);           // tokens never straddle b
  const int bh = b * Hc + h;

  const float tc = fminf(fmaxf(temp[h], 0.5f), 5.0f);
  const float k2 = 1.44269504f / tc;             // exp((sp-max)/t) == exp2((sp-max)*k2)

  // stage W_slice^T into LDS (read after the kb-loop barrier)
  #pragma unroll
  for (int it = 0; it < 2; ++it) {
    int s = it*32 + (tid >> 3), seg = tid & 7;
    *(f16x8*)&sm_ws[s*LDA + seg*8] = *(const f16x8*)&WsT[s*64 + seg*8];
  }

  // hoisted per-lane biases (col = nt*16 + ln in C-layout)
  float bv[8], bsv[4];
  #pragma unroll
  for (int nt = 0; nt < 4; ++nt) {
    bv[nt]   = bx [h*64 + nt*16 + ln];
    bv[nt+4] = bfx[h*64 + nt*16 + ln];
    bsv[nt]  = bsl[nt*16 + ln];
  }

  f32x4 Tacc[4];                                  // wave wv owns s in [wv*16, wv*16+16), all 64 d
  #pragma unroll
  for (int nt = 0; nt < 4; ++nt) Tacc[nt] = splat4(0.0f);
  float nacc[4] = {0.f, 0.f, 0.f, 0.f};           // per-lane partial slice_norm (s = nt*16+ln)

  const f16* WTh = WT + h * 128 * 256;

  for (int m0 = 0; m0 < 4; ++m0) {                // 4 sub-tiles of 64 tokens
    // ---------- Phase A: px|fx = x_tile @ [Wx_h | Wfx_h]  (M=64,N=128,K=256) ----------
    f32x4 acc[8];                                 // wave wv owns tokens [wv*16,+16), cols 0..127
    #pragma unroll
    for (int nt = 0; nt < 8; ++nt) acc[nt] = splat4(bv[nt]);   // bias as accumulator init

    for (int kb = 0; kb < 4; ++kb) {
      __syncthreads();                            // protects xt/wt (and fxT/wT) reuse
      {
        int r0 = tid >> 4, c4 = tid & 15;         // x: 64 rows x 64 f32, coalesced float4
        #pragma unroll
        for (int it = 0; it < 4; ++it) {
          int row = it*16 + r0;
          float4 v = *(const float4*)&x[(tokBase + m0*64 + row)*Cc + kb*64 + c4*4];
          f16x4 hv = { (f16)v.x, (f16)v.y, (f16)v.z, (f16)v.w };
          *(f16x4*)&sm_xt[row*LDA + c4*4] = hv;
        }
        int r1 = tid >> 3, seg = tid & 7;         // W: 128 rows x 64 f16
        #pragma unroll
        for (int it = 0; it < 4; ++it) {
          int n = it*32 + r1;
          *(f16x8*)&sm_wt[n*LDA + seg*8] = *(const f16x8*)&WTh[n*256 + kb*64 + seg*8];
        }
      }
      __syncthreads();
      #pragma unroll
      for (int ks = 0; ks < 2; ++ks) {
        f16x8 af = *(const f16x8*)&sm_xt[(wv*16 + ln)*LDA + ks*32 + quad*8];
        #pragma unroll
        for (int nt = 0; nt < 8; ++nt) {
          f16x8 bf = *(const f16x8*)&sm_wt[(nt*16 + ln)*LDA + ks*32 + quad*8];
          acc[nt] = MFMA(af, bf, acc[nt]);
        }
      }
    }
    // write px (A-layout [tok][d]) and fx^T (B-layout [d][tok]); C-layout: row=quad*4+rg, col=nt*16+ln
    #pragma unroll
    for (int nt = 0; nt < 4; ++nt) {
      #pragma unroll
      for (int rg = 0; rg < 4; ++rg) {
        int tk = wv*16 + quad*4 + rg;
        sm_px [tk*LDA + nt*16 + ln]   = (f16)acc[nt][rg];
        sm_fxT[(nt*16 + ln)*LDA + tk] = (f16)acc[nt+4][rg];
      }
    }
    __syncthreads();

    // ---------- Phase B: sp = px @ W_slice (M=64,N=64,K=64) + softmax ----------
    f32x4 sp[4];
    #pragma unroll
    for (int nt = 0; nt < 4; ++nt) sp[nt] = splat4(bsv[nt]);
    #pragma unroll
    for (int ks = 0; ks < 2; ++ks) {
      f16x8 af = *(const f16x8*)&sm_px[(wv*16 + ln)*LDA + ks*32 + quad*8];
      #pragma unroll
      for (int nt = 0; nt < 4; ++nt) {
        f16x8 bf = *(const f16x8*)&sm_ws[(nt*16 + ln)*LDA + ks*32 + quad*8];
        sp[nt] = MFMA(af, bf, sp[nt]);
      }
    }
    // softmax over s (row = token = wv*16 + quad*4 + rg; 64 s-values = 4 nt-tiles x 16 lanes)
    #pragma unroll
    for (int rg = 0; rg < 4; ++rg) {
      float m = fmaxf(fmaxf(sp[0][rg], sp[1][rg]), fmaxf(sp[2][rg], sp[3][rg]));
      #pragma unroll
      for (int dd = 1; dd < 16; dd <<= 1) m = fmaxf(m, __shfl_xor(m, dd, 64));
      float e0 = exp2f((sp[0][rg] - m) * k2);
      float e1 = exp2f((sp[1][rg] - m) * k2);
      float e2 = exp2f((sp[2][rg] - m) * k2);
      float e3 = exp2f((sp[3][rg] - m) * k2);
      float rs = e0 + e1 + e2 + e3;
      #pragma unroll
      for (int dd = 1; dd < 16; dd <<= 1) rs += __shfl_xor(rs, dd, 64);
      float inv = 1.0f / rs;
      float w0 = e0*inv, w1 = e1*inv, w2 = e2*inv, w3 = e3*inv;
      nacc[0] += w0; nacc[1] += w1; nacc[2] += w2; nacc[3] += w3;
      int tk = wv*16 + quad*4 + rg;
      sm_wT[(0*16 + ln)*LDA + tk] = (f16)w0;      // w^T: [s][tok]
      sm_wT[(1*16 + ln)*LDA + tk] = (f16)w1;
      sm_wT[(2*16 + ln)*LDA + tk] = (f16)w2;
      sm_wT[(3*16 + ln)*LDA + tk] = (f16)w3;
    }
    __syncthreads();

    // ---------- Phase C: T[s][d] += w^T @ fx (M=64,N=64,K=64tok) ----------
    #pragma unroll
    for (int ks = 0; ks < 2; ++ks) {
      f16x8 af = *(const f16x8*)&sm_wT[(wv*16 + ln)*LDA + ks*32 + quad*8];
      #pragma unroll
      for (int nt = 0; nt < 4; ++nt) {
        f16x8 bf = *(const f16x8*)&sm_fxT[(nt*16 + ln)*LDA + ks*32 + quad*8];
        Tacc[nt] = MFMA(af, bf, Tacc[nt]);
      }
    }
  }

  // ---------- flush: atomic accumulate to global ----------
  float* Tb = Tg + bh * 4096;
  #pragma unroll
  for (int nt = 0; nt < 4; ++nt) {
    #pragma unroll
    for (int rg = 0; rg < 4; ++rg) {
      int s = wv*16 + quad*4 + rg;
      atomicAdd(&Tb[s*64 + nt*16 + ln], Tacc[nt][rg]);
    }
  }
  #pragma unroll
  for (int nt = 0; nt < 4; ++nt) {
    float v = nacc[nt];
    v += __shfl_xor(v, 16, 64);                   // sum the 4 quads (disjoint tokens, same s)
    v += __shfl_xor(v, 32, 64);
    if (lane < 16) atomicAdd(&normg[bh*64 + nt*16 + ln], v);
  }
}

__global__ void finalize(const float* __restrict__ Tg, const float* __restrict__ normg,
                         float* __restrict__ out) {
  int i = blockIdx.x * 256 + threadIdx.x;         // 65536 outputs
  out[i] = Tg[i] / (normg[i >> 6] + 0.01f);
}

extern "C" void kernel_launch(void* const* d_in, const int* in_sizes, int n_in,
                              void* d_out, int out_size, void* d_ws, size_t ws_size,
                              hipStream_t stream) {
  const float* x    = (const float*)d_in[0];
  const float* Wx   = (const float*)d_in[1];
  const float* bx   = (const float*)d_in[2];
  const float* Wfx  = (const float*)d_in[3];
  const float* bfx  = (const float*)d_in[4];
  const float* Wsl  = (const float*)d_in[5];
  const float* bsl  = (const float*)d_in[6];
  const float* temp = (const float*)d_in[7];
  float* out = (float*)d_out;

  float* Tg    = (float*)d_ws;            // 65536 floats
  float* normg = Tg + 16 * 4096;          // 1024 floats
  f16*   WT    = (f16*)((char*)d_ws + 266240);
  f16*   WsT   = WT + 8 * 128 * 256;

  zero_ws   <<<260, 256, 0, stream>>>(Tg);                    // zero T + norm (66560 floats)
  prep_w    <<<528, 256, 0, stream>>>(Wx, Wfx, Wsl, WT, WsT); // f16-convert + transpose weights
  fused_main<<<dim3(NCHUNK, Hc), 256, 0, stream>>>(x, bx, bfx, bsl, temp, WT, WsT, Tg, normg);
  finalize  <<<256, 256, 0, stream>>>(Tg, normg, out);
}

// Round 2
// 443.914 us; speedup vs baseline: 1.0776x; 1.0776x over previous
//
#include <hip/hip_runtime.h>

typedef _Float16 f16;
typedef __attribute__((ext_vector_type(8))) _Float16 f16x8;
typedef __attribute__((ext_vector_type(4))) _Float16 f16x4;
typedef __attribute__((ext_vector_type(4))) float    f32x4;

#define MFMA(a,b,c) __builtin_amdgcn_mfma_f32_16x16x32_f16(a,b,c,0,0,0)

// problem constants
constexpr int Bc = 2, Nc = 65536, Cc = 256, Hc = 8, Dc = 64, Sc = 64;
constexpr int CHUNK  = 512;               // tokens per block (8 sub-tiles of 64)
constexpr int NCHUNK = Bc * Nc / CHUNK;   // 256
constexpr int LDA    = 72;                // padded f16 row stride: 144 B (16B-aligned, 2-way-free banks)

// ---- workspace layout (bytes) ----
// 0       : Tg    float[16*4096]  (262144)
// 262144  : normg float[16*64]    (4096)
// 266240  : WT    f16[8*128*256]  (524288)   [h][n(0..63=Wx col,64..127=Wfx col)][k]
// 790528  : WsT   f16[64*64]      (8192)     [s][d] = W_slice[d][s]

__device__ __forceinline__ f32x4 splat4(float v) { f32x4 r; r.x=v; r.y=v; r.z=v; r.w=v; return r; }

__global__ void prep_w(const float* __restrict__ Wx, const float* __restrict__ Wfx,
                       const float* __restrict__ Wsl, f16* __restrict__ WT,
                       f16* __restrict__ WsT) {
  int idx = blockIdx.x * 256 + threadIdx.x;
  if (idx < 256 * 512) {
    int k = idx >> 9, col = idx & 511;
    int h = col >> 6, n = col & 63;
    WT[(h*128 + n     )*256 + k] = (f16)Wx [idx];
    WT[(h*128 + 64 + n)*256 + k] = (f16)Wfx[idx];
  } else {
    int j = idx - 256 * 512;
    int s = j >> 6, d = j & 63;
    WsT[s*64 + d] = (f16)Wsl[d*64 + s];
  }
}

__global__ __launch_bounds__(256, 3)
void fused_main(const float* __restrict__ x,   const float* __restrict__ bx,
                const float* __restrict__ bfx, const float* __restrict__ bsl,
                const float* __restrict__ temp, const f16* __restrict__ WT,
                const f16* __restrict__ WsT,   float* __restrict__ Tg,
                float* __restrict__ normg) {
  // sm_a: x-tile staging, later aliased as px [tok][d]
  // sm_b: W-tile staging, later aliased as wT [s][tok] (rows 0..63)
  __shared__ alignas(16) f16 sm_a  [64  * LDA];   //  9216 B
  __shared__ alignas(16) f16 sm_b  [128 * LDA];   // 18432 B
  __shared__ alignas(16) f16 sm_fxT[64  * LDA];   //  9216 B  fx^T [d][tok]
  __shared__ alignas(16) f16 sm_ws [64  * LDA];   //  9216 B  W_slice^T [s][d]
  // total 46080 B -> 3 blocks/CU

  // XCD-swizzle: all 8 heads of a chunk land on one XCD (round-robin assumption)
  const int j    = blockIdx.x;
  const int xcd  = j & 7, slot = j >> 3;
  const int chunk = xcd * 32 + (slot >> 3);       // 0..255
  const int h     = slot & 7;

  const int tid = threadIdx.x;
  const int wv = tid >> 6, lane = tid & 63, quad = lane >> 4, ln = lane & 15;
  const int wm = wv >> 1, wn = wv & 1;            // 2x2 wave grid: wm=token half, wn=col half
  const long tokBase = (long)chunk * CHUNK;
  const int b  = (int)(tokBase >> 16);
  const int bh = b * Hc + h;

  const float tc = fminf(fmaxf(temp[h], 0.5f), 5.0f);
  const float k2 = 1.44269504f / tc;

  // stage W_slice^T
  #pragma unroll
  for (int it = 0; it < 2; ++it) {
    int s = it*32 + (tid >> 3), seg = tid & 7;
    *(f16x8*)&sm_ws[s*LDA + seg*8] = *(const f16x8*)&WsT[s*64 + seg*8];
  }

  // biases: phase-A col = wn*64 + nt*16 + ln
  float bv[4], bsv[4];
  const float* bias = wn ? (bfx + h*64) : (bx + h*64);
  #pragma unroll
  for (int nt = 0; nt < 4; ++nt) { bv[nt] = bias[nt*16 + ln]; bsv[nt] = bsl[nt*16 + ln]; }

  f32x4 Tacc[4];
  #pragma unroll
  for (int nt = 0; nt < 4; ++nt) Tacc[nt] = splat4(0.0f);
  float nacc[4] = {0.f, 0.f, 0.f, 0.f};

  const f16* WTh = WT + h * 128 * 256;

  // staging thread mapping
  const int xrow = tid >> 2, xseg = tid & 3;      // x: 64 rows x 64 f32, 4 float4/thread
  const int wrow = tid >> 1, whalf = tid & 1;     // W: 128 rows x 64 f16, 4 f16x8/thread

  float4 xr[4]; f16x8 wr[4];
  auto loadx = [&](int m0, int kb) {
    const float* p = x + (tokBase + m0*64 + xrow)*Cc + kb*64 + xseg*16;
    xr[0] = *(const float4*)p;       xr[1] = *(const float4*)(p + 4);
    xr[2] = *(const float4*)(p + 8); xr[3] = *(const float4*)(p + 12);
  };
  auto loadw = [&](int kb) {
    const f16* p = WTh + wrow*256 + kb*64 + whalf*32;
    wr[0] = *(const f16x8*)p;        wr[1] = *(const f16x8*)(p + 8);
    wr[2] = *(const f16x8*)(p + 16); wr[3] = *(const f16x8*)(p + 24);
  };

  loadx(0, 0); loadw(0);                           // software-pipeline head

  for (int m0 = 0; m0 < 8; ++m0) {
    // ---------- Phase A: px|fx = x_tile @ [Wx|Wfx], M=64,N=128,K=256 ----------
    f32x4 acc[2][4];
    #pragma unroll
    for (int mt = 0; mt < 2; ++mt)
      #pragma unroll
      for (int nt = 0; nt < 4; ++nt) acc[mt][nt] = splat4(bv[nt]);

    for (int kb = 0; kb < 4; ++kb) {
      __syncthreads();                             // prev reads of sm_a/sm_b done
      { // store prefetched regs -> LDS (conflict-free patterns)
        f16x8 h0 = { (f16)xr[0].x,(f16)xr[0].y,(f16)xr[0].z,(f16)xr[0].w,
                     (f16)xr[1].x,(f16)xr[1].y,(f16)xr[1].z,(f16)xr[1].w };
        f16x8 h1 = { (f16)xr[2].x,(f16)xr[2].y,(f16)xr[2].z,(f16)xr[2].w,
                     (f16)xr[3].x,(f16)xr[3].y,(f16)xr[3].z,(f16)xr[3].w };
        *(f16x8*)&sm_a[xrow*LDA + xseg*16]     = h0;
        *(f16x8*)&sm_a[xrow*LDA + xseg*16 + 8] = h1;
        *(f16x8*)&sm_b[wrow*LDA + whalf*32]      = wr[0];
        *(f16x8*)&sm_b[wrow*LDA + whalf*32 +  8] = wr[1];
        *(f16x8*)&sm_b[wrow*LDA + whalf*32 + 16] = wr[2];
        *(f16x8*)&sm_b[wrow*LDA + whalf*32 + 24] = wr[3];
      }
      { // prefetch next (m0,kb) — completes during MFMAs / epilogue
        int nkb = kb + 1, nm0 = m0;
        if (nkb == 4) { nkb = 0; nm0 = m0 + 1; }
        if (nm0 < 8) { loadx(nm0, nkb); loadw(nkb); }
      }
      __syncthreads();
      #pragma unroll
      for (int ks = 0; ks < 2; ++ks) {
        f16x8 a0 = *(const f16x8*)&sm_a[(wm*32 +      ln)*LDA + ks*32 + quad*8];
        f16x8 a1 = *(const f16x8*)&sm_a[(wm*32 + 16 + ln)*LDA + ks*32 + quad*8];
        #pragma unroll
        for (int nt = 0; nt < 4; ++nt) {
          f16x8 bf = *(const f16x8*)&sm_b[(wn*64 + nt*16 + ln)*LDA + ks*32 + quad*8];
          acc[0][nt] = MFMA(a0, bf, acc[0][nt]);
          acc[1][nt] = MFMA(a1, bf, acc[1][nt]);
        }
      }
    }
    __syncthreads();                               // all phase-A reads done before alias overwrite

    // write px -> sm_a [tok][d] (wn==0 waves), fx^T -> sm_fxT [d][tok] (wn==1, packed f16x4)
    if (wn == 0) {
      #pragma unroll
      for (int mt = 0; mt < 2; ++mt)
        #pragma unroll
        for (int nt = 0; nt < 4; ++nt)
          #pragma unroll
          for (int rg = 0; rg < 4; ++rg)
            sm_a[(wm*32 + mt*16 + quad*4 + rg)*LDA + nt*16 + ln] = (f16)acc[mt][nt][rg];
    } else {
      #pragma unroll
      for (int mt = 0; mt < 2; ++mt)
        #pragma unroll
        for (int nt = 0; nt < 4; ++nt) {
          f16x4 v = { (f16)acc[mt][nt][0], (f16)acc[mt][nt][1],
                      (f16)acc[mt][nt][2], (f16)acc[mt][nt][3] };
          *(f16x4*)&sm_fxT[(nt*16 + ln)*LDA + wm*32 + mt*16 + quad*4] = v;
        }
    }
    __syncthreads();

    // ---------- Phase B: sp = px @ Ws (M=64,N=64,K=64) + softmax ----------
    f32x4 sp[4];
    #pragma unroll
    for (int nt = 0; nt < 4; ++nt) sp[nt] = splat4(bsv[nt]);
    #pragma unroll
    for (int ks = 0; ks < 2; ++ks) {
      f16x8 af = *(const f16x8*)&sm_a[(wv*16 + ln)*LDA + ks*32 + quad*8];
      #pragma unroll
      for (int nt = 0; nt < 4; ++nt) {
        f16x8 bf = *(const f16x8*)&sm_ws[(nt*16 + ln)*LDA + ks*32 + quad*8];
        sp[nt] = MFMA(af, bf, sp[nt]);
      }
    }
    float wreg[4][4];
    #pragma unroll
    for (int rg = 0; rg < 4; ++rg) {
      float m = fmaxf(fmaxf(sp[0][rg], sp[1][rg]), fmaxf(sp[2][rg], sp[3][rg]));
      #pragma unroll
      for (int dd = 1; dd < 16; dd <<= 1) m = fmaxf(m, __shfl_xor(m, dd, 64));
      float e0 = exp2f((sp[0][rg] - m) * k2);
      float e1 = exp2f((sp[1][rg] - m) * k2);
      float e2 = exp2f((sp[2][rg] - m) * k2);
      float e3 = exp2f((sp[3][rg] - m) * k2);
      float rs = e0 + e1 + e2 + e3;
      #pragma unroll
      for (int dd = 1; dd < 16; dd <<= 1) rs += __shfl_xor(rs, dd, 64);
      float inv = 1.0f / rs;
      wreg[0][rg] = e0*inv; wreg[1][rg] = e1*inv; wreg[2][rg] = e2*inv; wreg[3][rg] = e3*inv;
      nacc[0] += wreg[0][rg]; nacc[1] += wreg[1][rg];
      nacc[2] += wreg[2][rg]; nacc[3] += wreg[3][rg];
    }
    #pragma unroll
    for (int nt = 0; nt < 4; ++nt) {              // wT [s][tok], packed f16x4
      f16x4 v = { (f16)wreg[nt][0], (f16)wreg[nt][1], (f16)wreg[nt][2], (f16)wreg[nt][3] };
      *(f16x4*)&sm_b[(nt*16 + ln)*LDA + wv*16 + quad*4] = v;
    }
    __syncthreads();

    // ---------- Phase C: T[s][d] += w^T @ fx (K=64 tokens) ----------
    #pragma unroll
    for (int ks = 0; ks < 2; ++ks) {
      f16x8 af = *(const f16x8*)&sm_b[(wv*16 + ln)*LDA + ks*32 + quad*8];
      #pragma unroll
      for (int nt = 0; nt < 4; ++nt) {
        f16x8 bf = *(const f16x8*)&sm_fxT[(nt*16 + ln)*LDA + ks*32 + quad*8];
        Tacc[nt] = MFMA(af, bf, Tacc[nt]);
      }
    }
  }

  // ---------- flush ----------
  float* Tb = Tg + bh * 4096;
  #pragma unroll
  for (int nt = 0; nt < 4; ++nt) {
    #pragma unroll
    for (int rg = 0; rg < 4; ++rg) {
      int s = wv*16 + quad*4 + rg;
      atomicAdd(&Tb[s*64 + nt*16 + ln], Tacc[nt][rg]);
    }
  }
  #pragma unroll
  for (int nt = 0; nt < 4; ++nt) {
    float v = nacc[nt];
    v += __shfl_xor(v, 16, 64);
    v += __shfl_xor(v, 32, 64);
    if (lane < 16) atomicAdd(&normg[bh*64 + nt*16 + ln], v);
  }
}

__global__ void finalize(const float* __restrict__ Tg, const float* __restrict__ normg,
                         float* __restrict__ out) {
  int i = blockIdx.x * 256 + threadIdx.x;
  out[i] = Tg[i] / (normg[i >> 6] + 0.01f);
}

extern "C" void kernel_launch(void* const* d_in, const int* in_sizes, int n_in,
                              void* d_out, int out_size, void* d_ws, size_t ws_size,
                              hipStream_t stream) {
  const float* x    = (const float*)d_in[0];
  const float* Wx   = (const float*)d_in[1];
  const float* bx   = (const float*)d_in[2];
  const float* Wfx  = (const float*)d_in[3];
  const float* bfx  = (const float*)d_in[4];
  const float* Wsl  = (const float*)d_in[5];
  const float* bsl  = (const float*)d_in[6];
  const float* temp = (const float*)d_in[7];
  float* out = (float*)d_out;

  float* Tg    = (float*)d_ws;
  float* normg = Tg + 16 * 4096;
  f16*   WT    = (f16*)((char*)d_ws + 266240);
  f16*   WsT   = WT + 8 * 128 * 256;

  hipMemsetAsync(d_ws, 0, 266240, stream);                    // zero Tg + normg
  prep_w    <<<528, 256, 0, stream>>>(Wx, Wfx, Wsl, WT, WsT);
  fused_main<<<NCHUNK * Hc, 256, 0, stream>>>(x, bx, bfx, bsl, temp, WT, WsT, Tg, normg);
  finalize  <<<256, 256, 0, stream>>>(Tg, normg, out);
}

// Round 3
// 368.108 us; speedup vs baseline: 1.2995x; 1.2059x over previous
//
#include <hip/hip_runtime.h>

typedef _Float16 f16;
typedef __attribute__((ext_vector_type(8))) _Float16 f16x8;
typedef __attribute__((ext_vector_type(4))) _Float16 f16x4;
typedef __attribute__((ext_vector_type(4))) float    f32x4;

#define MFMA(a,b,c) __builtin_amdgcn_mfma_f32_16x16x32_f16(a,b,c,0,0,0)

// problem constants
constexpr int Bc = 2, Nc = 65536, Cc = 256, Hc = 8;
constexpr int CHUNK = 512;                 // tokens per block: 4 m0-tiles of 128
constexpr int LDX = 72;                    // x/W stage stride (f16): rows 16B-aligned, conflict-free frags
constexpr int LDT = 136;                   // fxT/wT stride (f16): rows 16B-aligned, conflict-free frags

// ---- workspace layout (bytes) ----
// 0      : Tg    float[16*4096] (262144)   unnormalized slice_tokens accumulator
// 262144 : normg float[16*64]   (4096)
// 266240 : WC    f16[8*128*256] (524288)   [h][n][k]; n 0..63 = Wfx cols, n 64..127 = Wxs = Wx_h@Ws cols
// 790528 : bsp   float[8*64]    (2048)     folded slice bias: bx_h@Ws + bsl
// total 792576  (< round-1's 798720, known to fit)

__device__ __forceinline__ f32x4 splat4(float v) { f32x4 r; r.x=v; r.y=v; r.z=v; r.w=v; return r; }
__device__ __forceinline__ f16x8 pack8(float4 a, float4 b) {
  f16x8 r = { (f16)a.x,(f16)a.y,(f16)a.z,(f16)a.w,(f16)b.x,(f16)b.y,(f16)b.z,(f16)b.w };
  return r;
}

// One prep kernel, 65 blocks:
//  b 0..31 : LDS-tiled transpose of Wfx -> WC fx rows (coalesced reads AND writes)
//  b 32..63: Wxs_h = Wx_h @ Ws  (f32, L1-resident strided reads, coalesced writes)
//  b 64    : bsp
__global__ void prep_a(const float* __restrict__ Wx, const float* __restrict__ Wfx,
                       const float* __restrict__ Wsl, const float* __restrict__ bx,
                       const float* __restrict__ bsl, f16* __restrict__ WC,
                       float* __restrict__ bsp) {
  __shared__ float tile[64][72];
  const int b = blockIdx.x, t = threadIdx.x;
  if (b < 32) {                            // transpose Wfx tile (k0..+64) x (c0..+64)
    const int k0 = (b & 3) * 64, c0 = (b >> 2) * 64;
    const int r = t >> 4, c4 = (t & 15) * 4;
    #pragma unroll
    for (int i = 0; i < 4; ++i) {
      float4 v = *(const float4*)&Wfx[(size_t)(k0 + r + i*16)*512 + c0 + c4];
      tile[r + i*16][c4] = v.x; tile[r + i*16][c4+1] = v.y;
      tile[r + i*16][c4+2] = v.z; tile[r + i*16][c4+3] = v.w;
    }
    __syncthreads();
    const int cl = t >> 2, kq = t & 3;
    const int col = c0 + cl, h = col >> 6, n = col & 63;
    f16 tmp[16];
    #pragma unroll
    for (int j = 0; j < 16; ++j) tmp[j] = (f16)tile[kq*16 + j][cl];
    f16* dst = WC + (size_t)(h*128 + n)*256 + k0 + kq*16;
    *(f16x8*)dst       = *(f16x8*)&tmp[0];
    *(f16x8*)(dst + 8) = *(f16x8*)&tmp[8];
  } else if (b < 64) {                     // Wxs: rows k0..+64 of Wx_h @ Ws
    const int k0 = ((b - 32) & 3) * 64, h = (b - 32) >> 2;
    const int k = t & 63, sq = t >> 6;     // each thread: 1 k-row, 16 s-cols
    float accs[16];
    #pragma unroll
    for (int j = 0; j < 16; ++j) accs[j] = 0.f;
    for (int d = 0; d < 64; ++d) {
      float a = Wx[(size_t)(k0 + k)*512 + h*64 + d];   // L1-resident after first lines
      #pragma unroll
      for (int j = 0; j < 16; ++j) accs[j] += a * Wsl[d*64 + sq*16 + j];
    }
    #pragma unroll
    for (int j = 0; j < 16; ++j)           // lanes k consecutive -> 128B coalesced
      WC[(size_t)(h*128 + 64 + sq*16 + j)*256 + k0 + k] = (f16)accs[j];
  } else {                                 // bsp[h][s] = sum_d bx[h,d]*Ws[d][s] + bsl[s]
    for (int u = t; u < 512; u += 256) {
      int h = u >> 6, s = u & 63;
      float a = bsl[s];
      for (int d = 0; d < 64; ++d) a += bx[h*64 + d] * Wsl[d*64 + s];
      bsp[h*64 + s] = a;
    }
  }
}

__global__ __launch_bounds__(256, 2)
void fused_main(const float* __restrict__ x,   const float* __restrict__ bfx,
                const float* __restrict__ bsp, const float* __restrict__ temp,
                const f16* __restrict__ WC,    float* __restrict__ Tg,
                float* __restrict__ normg) {
  __shared__ alignas(16) f16 sm_x  [128 * LDX];  // 18432 B  x sub-tile [tok128][k64]
  __shared__ alignas(16) f16 sm_w  [128 * LDX];  // 18432 B  W tile [n128][k64]
  __shared__ alignas(16) f16 sm_fxT[64  * LDT];  // 17408 B  fx^T [d64][tok128]
  __shared__ alignas(16) f16 sm_wT [64  * LDT];  // 17408 B  w^T  [s64][tok128]
  // total 71680 B -> 2 blocks/CU

  // XCD swizzle: all 8 heads of a chunk on one XCD
  const int j    = blockIdx.x;
  const int xcd  = j & 7, slot = j >> 3;
  const int chunk = xcd * 32 + (slot >> 3);      // 0..255
  const int h     = slot & 7;

  const int tid = threadIdx.x;
  const int wv = tid >> 6, lane = tid & 63, quad = lane >> 4, ln = lane & 15;
  const int wm = wv >> 1, wn = wv & 1;           // phase-A wave grid: wm = 64-token half, wn = col half
  const long tokBase = (long)chunk * CHUNK;
  const int b  = (int)(tokBase >> 16);
  const int bh = b * Hc + h;

  const float tc = fminf(fmaxf(temp[h], 0.5f), 5.0f);
  const float k2 = 1.44269504f / tc;

  // biases: wn==0 -> fx cols (bfx), wn==1 -> sp cols (bsp, includes bsl fold)
  float bv[4];
  {
    const float* bb = (wn == 0) ? (bfx + h*64) : (bsp + h*64);
    #pragma unroll
    for (int nt = 0; nt < 4; ++nt) bv[nt] = bb[nt*16 + ln];
  }

  f32x4 Tacc[2][2];                               // phase-C acc: wave (ci,cj): s 32ci..+32, d 32cj..+32
  #pragma unroll
  for (int i = 0; i < 2; ++i) { Tacc[i][0] = splat4(0.f); Tacc[i][1] = splat4(0.f); }
  float nacc[4] = {0.f, 0.f, 0.f, 0.f};
  const int ci = wv >> 1, cj = wv & 1;

  const f16* WCh = WC + (size_t)h * 128 * 256;

  // staging maps
  const int r0 = tid >> 2, seg = tid & 3;        // x: rows r0, r0+64; cols seg*16..+16
  const int wrow = tid >> 1, whalf = tid & 1;    // W: row wrow; cols whalf*32..+32

  float4 xr[8]; f16x8 wr[4];
  auto loadx = [&](int m0, int kb) {
    const float* p = x + (tokBase + (long)m0*128 + r0)*Cc + kb*64 + seg*16;
    xr[0] = *(const float4*)p;        xr[1] = *(const float4*)(p + 4);
    xr[2] = *(const float4*)(p + 8);  xr[3] = *(const float4*)(p + 12);
    p += 64 * Cc;
    xr[4] = *(const float4*)p;        xr[5] = *(const float4*)(p + 4);
    xr[6] = *(const float4*)(p + 8);  xr[7] = *(const float4*)(p + 12);
  };
  auto loadw = [&](int kb) {
    const f16* p = WCh + wrow*256 + kb*64 + whalf*32;
    wr[0] = *(const f16x8*)p;         wr[1] = *(const f16x8*)(p + 8);
    wr[2] = *(const f16x8*)(p + 16);  wr[3] = *(const f16x8*)(p + 24);
  };

  loadx(0, 0); loadw(0);

  for (int m0 = 0; m0 < 4; ++m0) {
    // ---------- Phase A: [fx | sp] = x_tile(128x256) @ WC_h(256x128), wave tile 64x64 ----------
    f32x4 acc[4][4];
    #pragma unroll
    for (int mt = 0; mt < 4; ++mt)
      #pragma unroll
      for (int nt = 0; nt < 4; ++nt) acc[mt][nt] = splat4(bv[nt]);

    for (int kb = 0; kb < 4; ++kb) {
      __syncthreads();
      *(f16x8*)&sm_x[r0*LDX + seg*16]          = pack8(xr[0], xr[1]);
      *(f16x8*)&sm_x[r0*LDX + seg*16 + 8]      = pack8(xr[2], xr[3]);
      *(f16x8*)&sm_x[(r0+64)*LDX + seg*16]     = pack8(xr[4], xr[5]);
      *(f16x8*)&sm_x[(r0+64)*LDX + seg*16 + 8] = pack8(xr[6], xr[7]);
      *(f16x8*)&sm_w[wrow*LDX + whalf*32]      = wr[0];
      *(f16x8*)&sm_w[wrow*LDX + whalf*32 +  8] = wr[1];
      *(f16x8*)&sm_w[wrow*LDX + whalf*32 + 16] = wr[2];
      *(f16x8*)&sm_w[wrow*LDX + whalf*32 + 24] = wr[3];
      { int nkb = kb + 1, nm0 = m0;
        if (nkb == 4) { nkb = 0; ++nm0; }
        if (nm0 < 4) { loadx(nm0, nkb); loadw(nkb); } }
      __syncthreads();
      #pragma unroll
      for (int ks = 0; ks < 2; ++ks) {
        f16x8 af[4], bf[4];
        #pragma unroll
        for (int mt = 0; mt < 4; ++mt)
          af[mt] = *(const f16x8*)&sm_x[(wm*64 + mt*16 + ln)*LDX + ks*32 + quad*8];
        #pragma unroll
        for (int nt = 0; nt < 4; ++nt)
          bf[nt] = *(const f16x8*)&sm_w[(wn*64 + nt*16 + ln)*LDX + ks*32 + quad*8];
        #pragma unroll
        for (int mt = 0; mt < 4; ++mt)
          #pragma unroll
          for (int nt = 0; nt < 4; ++nt)
            acc[mt][nt] = MFMA(af[mt], bf[nt], acc[mt][nt]);
      }
    }

    // ---------- epilogue: fx waves -> fx^T; sp waves -> softmax -> w^T (all f16x4, conflict-free) ----------
    if (wn == 0) {
      #pragma unroll
      for (int mt = 0; mt < 4; ++mt)
        #pragma unroll
        for (int nt = 0; nt < 4; ++nt) {
          f16x4 v = { (f16)acc[mt][nt][0], (f16)acc[mt][nt][1],
                      (f16)acc[mt][nt][2], (f16)acc[mt][nt][3] };
          *(f16x4*)&sm_fxT[(nt*16 + ln)*LDT + wm*64 + mt*16 + quad*4] = v;
        }
    } else {
      #pragma unroll
      for (int mt = 0; mt < 4; ++mt) {
        float wreg[4][4];
        #pragma unroll
        for (int rg = 0; rg < 4; ++rg) {
          float m = fmaxf(fmaxf(acc[mt][0][rg], acc[mt][1][rg]),
                          fmaxf(acc[mt][2][rg], acc[mt][3][rg]));
          #pragma unroll
          for (int dd = 1; dd < 16; dd <<= 1) m = fmaxf(m, __shfl_xor(m, dd, 64));
          float e0 = exp2f((acc[mt][0][rg] - m) * k2);
          float e1 = exp2f((acc[mt][1][rg] - m) * k2);
          float e2 = exp2f((acc[mt][2][rg] - m) * k2);
          float e3 = exp2f((acc[mt][3][rg] - m) * k2);
          float rs = e0 + e1 + e2 + e3;
          #pragma unroll
          for (int dd = 1; dd < 16; dd <<= 1) rs += __shfl_xor(rs, dd, 64);
          float inv = 1.0f / rs;
          wreg[0][rg] = e0*inv; wreg[1][rg] = e1*inv;
          wreg[2][rg] = e2*inv; wreg[3][rg] = e3*inv;
          nacc[0] += wreg[0][rg]; nacc[1] += wreg[1][rg];
          nacc[2] += wreg[2][rg]; nacc[3] += wreg[3][rg];
        }
        #pragma unroll
        for (int nt = 0; nt < 4; ++nt) {
          f16x4 v = { (f16)wreg[nt][0], (f16)wreg[nt][1],
                      (f16)wreg[nt][2], (f16)wreg[nt][3] };
          *(f16x4*)&sm_wT[(nt*16 + ln)*LDT + wm*64 + mt*16 + quad*4] = v;
        }
      }
    }
    __syncthreads();

    // ---------- Phase C: T[s][d] += w^T @ fx, K=128 tokens, wave tile 32x32 ----------
    #pragma unroll
    for (int ks = 0; ks < 4; ++ks) {
      f16x8 a0 = *(const f16x8*)&sm_wT [(ci*32 +      ln)*LDT + ks*32 + quad*8];
      f16x8 a1 = *(const f16x8*)&sm_wT [(ci*32 + 16 + ln)*LDT + ks*32 + quad*8];
      f16x8 b0 = *(const f16x8*)&sm_fxT[(cj*32 +      ln)*LDT + ks*32 + quad*8];
      f16x8 b1 = *(const f16x8*)&sm_fxT[(cj*32 + 16 + ln)*LDT + ks*32 + quad*8];
      Tacc[0][0] = MFMA(a0, b0, Tacc[0][0]);
      Tacc[0][1] = MFMA(a0, b1, Tacc[0][1]);
      Tacc[1][0] = MFMA(a1, b0, Tacc[1][0]);
      Tacc[1][1] = MFMA(a1, b1, Tacc[1][1]);
    }
    // next m0's first barrier orders phase-C reads vs epilogue rewrites
  }

  // ---------- flush ----------
  float* Tb = Tg + bh * 4096;
  #pragma unroll
  for (int mt2 = 0; mt2 < 2; ++mt2)
    #pragma unroll
    for (int nt2 = 0; nt2 < 2; ++nt2)
      #pragma unroll
      for (int rg = 0; rg < 4; ++rg) {
        int s = ci*32 + mt2*16 + quad*4 + rg;
        int d = cj*32 + nt2*16 + ln;
        atomicAdd(&Tb[s*64 + d], Tacc[mt2][nt2][rg]);
      }
  if (wn == 1) {
    #pragma unroll
    for (int nt = 0; nt < 4; ++nt) {
      float v = nacc[nt];
      v += __shfl_xor(v, 16, 64);
      v += __shfl_xor(v, 32, 64);
      if (lane < 16) atomicAdd(&normg[bh*64 + nt*16 + ln], v);
    }
  }
}

__global__ void finalize(const float* __restrict__ Tg, const float* __restrict__ normg,
                         float* __restrict__ out) {
  int i = blockIdx.x * 256 + threadIdx.x;
  out[i] = Tg[i] / (normg[i >> 6] + 0.01f);
}

extern "C" void kernel_launch(void* const* d_in, const int* in_sizes, int n_in,
                              void* d_out, int out_size, void* d_ws, size_t ws_size,
                              hipStream_t stream) {
  const float* x    = (const float*)d_in[0];
  const float* Wx   = (const float*)d_in[1];
  const float* bx   = (const float*)d_in[2];
  const float* Wfx  = (const float*)d_in[3];
  const float* bfx  = (const float*)d_in[4];
  const float* Wsl  = (const float*)d_in[5];
  const float* bsl  = (const float*)d_in[6];
  const float* temp = (const float*)d_in[7];
  float* out = (float*)d_out;

  float* Tg    = (float*)d_ws;
  float* normg = Tg + 16 * 4096;
  f16*   WC    = (f16*)((char*)d_ws + 266240);
  float* bsp   = (float*)((char*)d_ws + 790528);

  hipMemsetAsync(d_ws, 0, 266240, stream);       // zero Tg + normg
  prep_a    <<<65, 256, 0, stream>>>(Wx, Wfx, Wsl, bx, bsl, WC, bsp);
  fused_main<<<256 * Hc * (CHUNK/512) * 1, 256, 0, stream>>>(x, bfx, bsp, temp, WC, Tg, normg);
  finalize  <<<256, 256, 0, stream>>>(Tg, normg, out);
}